// Round 3
// baseline (187.802 us; speedup 1.0000x reference)
//
#include <hip/hip_runtime.h>

// ---------------------------------------------------------------------------
// MultiHeadAttention (B=2, E=512, H=8, T=2048, DH=64), fp32 in/out.
//   K1 wstd:   weight-standardize Wq/Wk/Wv/Wo -> bf16; also key_mask -> fp32
//   K2 trans:  x[b][i][t]*mask[t] -> xT[src][b][t][i] bf16   (masks folded)
//   K3 proj:   Y = Wn @ xT^T + bias, per-head LN fused; XOR-swizzled LDS
//              Q,K -> bf16 [B][H][T][DH]; V -> f16 [B][H][DH][T]
//   K4 attn:   S^T register-softmax flash attention: QK^T via bf16 K=32 MFMA
//              (D = S^T, whose C-layout IS the A-layout of K=16 MFMA),
//              exp in registers, PV via f16 16x16x16 MFMA. No LDS in loop.
//   K5 oproj:  out = WnO @ xa^T + bo -> fp32; 64x64 tiles (512 blocks)
// ---------------------------------------------------------------------------

typedef __bf16 bf16;
typedef __bf16 bf16x8 __attribute__((ext_vector_type(8)));
typedef _Float16 f16;
typedef _Float16 f16x4 __attribute__((ext_vector_type(4)));
typedef float  f32x4  __attribute__((ext_vector_type(4)));

#define MFMA_BF16(a, b, c) __builtin_amdgcn_mfma_f32_16x16x32_bf16((a), (b), (c), 0, 0, 0)
#define MFMA_F16_K16(a, b, c) __builtin_amdgcn_mfma_f32_16x16x16f16((a), (b), (c), 0, 0, 0)

#define NB   2
#define NE   512
#define NH   8
#define NT   2048
#define NDH  64

__device__ __forceinline__ void gl_lds16(const bf16* g, bf16* l) {
  __builtin_amdgcn_global_load_lds(
      (const __attribute__((address_space(1))) void*)g,
      (__attribute__((address_space(3))) void*)l, 16, 0, 0);
}

// ---------------- K1: weight standardization + mask cast -------------------
__global__ __launch_bounds__(64) void k_wstd(
    const float* __restrict__ Wq, const float* __restrict__ Wk,
    const float* __restrict__ Wv, const float* __restrict__ Wo,
    const int* __restrict__ km,
    bf16* __restrict__ out, float* __restrict__ kmf)
{
  if (blockIdx.y == 4) {   // key_mask int -> float
    int idx = blockIdx.x * 64 + threadIdx.x;
    if (idx < NB * NT) kmf[idx] = (float)km[idx];
    return;
  }
  const float* W = blockIdx.y == 0 ? Wq : blockIdx.y == 1 ? Wk
                 : blockIdx.y == 2 ? Wv : Wo;
  int row = blockIdx.x, lane = threadIdx.x;
  const float4* p = (const float4*)(W + row * NE) + lane * 2;
  float4 a = p[0], c = p[1];
  float s  = a.x + a.y + a.z + a.w + c.x + c.y + c.z + c.w;
  float ss = a.x*a.x + a.y*a.y + a.z*a.z + a.w*a.w
           + c.x*c.x + c.y*c.y + c.z*c.z + c.w*c.w;
#pragma unroll
  for (int m = 1; m < 64; m <<= 1) { s += __shfl_xor(s, m); ss += __shfl_xor(ss, m); }
  float mean = s * (1.0f / NE);
  float var  = ss * (1.0f / NE) - mean * mean;
  float rstd = rsqrtf(var + 1e-5f);
  bf16x8 o;
  o[0] = (bf16)((a.x - mean) * rstd); o[1] = (bf16)((a.y - mean) * rstd);
  o[2] = (bf16)((a.z - mean) * rstd); o[3] = (bf16)((a.w - mean) * rstd);
  o[4] = (bf16)((c.x - mean) * rstd); o[5] = (bf16)((c.y - mean) * rstd);
  o[6] = (bf16)((c.z - mean) * rstd); o[7] = (bf16)((c.w - mean) * rstd);
  *(bf16x8*)(out + blockIdx.y * (NE * NE) + row * NE + lane * 8) = o;
}

// ---------------- K2: transpose + mask + cast ------------------------------
__global__ __launch_bounds__(256) void k_trans(
    const float* __restrict__ q, const float* __restrict__ k,
    const float* __restrict__ v,
    const int* __restrict__ qm, const int* __restrict__ km,
    const int* __restrict__ vm,
    bf16* __restrict__ xT)
{
  int src = blockIdx.z >> 1, b = blockIdx.z & 1;
  const float* x = src == 0 ? q : src == 1 ? k : v;
  const int*   m = src == 0 ? qm : src == 1 ? km : vm;
  x += (size_t)b * NE * NT;
  m += b * NT;
  int t0 = blockIdx.x * 64, i0 = blockIdx.y * 64;
  __shared__ float tile[64][65];
  int tt = threadIdx.x & 63, ii = threadIdx.x >> 6;
#pragma unroll
  for (int i = ii; i < 64; i += 4)
    tile[i][tt] = x[(size_t)(i0 + i) * NT + t0 + tt];
  __syncthreads();
  bf16* o = xT + ((size_t)src * NB + b) * NT * NE;
  int i2 = threadIdx.x & 63, t2 = threadIdx.x >> 6;
#pragma unroll
  for (int t = t2; t < 64; t += 4) {
    float mk = (float)m[t0 + t];
    o[(size_t)(t0 + t) * NE + i0 + i2] = (bf16)(tile[i2][t] * mk);
  }
}

// ---------------- K3: projection GEMM + fused per-head LN ------------------
__global__ __launch_bounds__(256) void k_proj(
    const bf16* __restrict__ Wn,   // [3+1][512][512]
    const bf16* __restrict__ xT,   // [3][B][T][E]
    const float* __restrict__ bq, const float* __restrict__ bk,
    const float* __restrict__ bv,
    const float* __restrict__ gq, const float* __restrict__ bbq,
    const float* __restrict__ gk, const float* __restrict__ bbk,
    const float* __restrict__ gv, const float* __restrict__ bbv,
    bf16* __restrict__ Qh, bf16* __restrict__ Kh, f16* __restrict__ Vh)
{
  int src = blockIdx.z >> 1, b = blockIdx.z & 1;
  const bf16* A  = Wn + src * (NE * NE);
  const bf16* Bm = xT + ((size_t)src * NB + b) * NT * NE;
  int m0 = blockIdx.y * 64, n0 = blockIdx.x * 128;
  int h = m0 >> 6;

  __shared__ __align__(16) char smem[64 * 130 * 4 + 2 * 128 * 4]; // 34304 B
  bf16*  Al = (bf16*)smem;            // [64][64] swizzled
  bf16*  Bl = (bf16*)(smem + 8192);   // [128][64] swizzled
  float* Yl = (float*)smem;           // [64][130]
  float* mu = (float*)(smem + 64 * 130 * 4);
  float* rs = mu + 128;

  int tid = threadIdx.x, lane = tid & 63, w = tid >> 6;
  int mh = (w & 1) * 32, nh = (w >> 1) * 64;
  f32x4 acc[2][4] = {};

  for (int k0 = 0; k0 < NE; k0 += 64) {
    __syncthreads();
#pragma unroll
    for (int i = 0; i < 2; i++) {
      int row = (w << 4) + (i << 3) + (lane >> 3);
      int chg = (lane & 7) ^ (row & 7);
      gl_lds16(A + (m0 + row) * NE + k0 + (chg << 3),
               Al + ((w << 4) + (i << 3)) * 64);
    }
#pragma unroll
    for (int i = 0; i < 4; i++) {
      int row = (w << 5) + (i << 3) + (lane >> 3);
      int chg = (lane & 7) ^ (row & 7);
      gl_lds16(Bm + (size_t)(n0 + row) * NE + k0 + (chg << 3),
               Bl + ((w << 5) + (i << 3)) * 64);
    }
    __syncthreads();
#pragma unroll
    for (int kk = 0; kk < 64; kk += 32) {
      bf16x8 af[2], bfv[4];
#pragma unroll
      for (int ms = 0; ms < 2; ms++) {
        int row = mh + ms * 16 + (lane & 15);
        af[ms] = *(const bf16x8*)(Al + row * 64 +
                   ((((kk >> 3) + (lane >> 4)) ^ (row & 7)) << 3));
      }
#pragma unroll
      for (int ns = 0; ns < 4; ns++) {
        int row = nh + ns * 16 + (lane & 15);
        bfv[ns] = *(const bf16x8*)(Bl + row * 64 +
                   ((((kk >> 3) + (lane >> 4)) ^ (row & 7)) << 3));
      }
#pragma unroll
      for (int ms = 0; ms < 2; ms++)
#pragma unroll
        for (int ns = 0; ns < 4; ns++)
          acc[ms][ns] = MFMA_BF16(af[ms], bfv[ns], acc[ms][ns]);
    }
  }

  __syncthreads();
  {
    const float* bias = src == 0 ? bq : src == 1 ? bk : bv;
#pragma unroll
    for (int ms = 0; ms < 2; ms++)
#pragma unroll
      for (int ns = 0; ns < 4; ns++)
#pragma unroll
        for (int r = 0; r < 4; r++) {
          int om = mh + ms * 16 + ((lane >> 4) << 2) + r;
          int on = nh + ns * 16 + (lane & 15);
          Yl[om * 130 + on] = acc[ms][ns][r] + bias[m0 + om];
        }
  }
  __syncthreads();
  if (tid < 128) {
    float s = 0.f, ss = 0.f;
#pragma unroll 8
    for (int o = 0; o < 64; o++) { float y = Yl[o * 130 + tid]; s += y; ss += y * y; }
    float mean = s * (1.0f / 64.0f);
    float var  = ss * (1.0f / 64.0f) - mean * mean;
    mu[tid] = mean;
    rs[tid] = rsqrtf(var + 1e-5f);
  }
  __syncthreads();

  if (src < 2) {
    float scl = (src == 0) ? (1.0f / 181.0f) : 1.0f;  // SCALE = 512//sqrt(8)
    const float* g  = src == 0 ? gq  : gk;
    const float* bb = src == 0 ? bbq : bbk;
    bf16* out = (src == 0 ? Qh : Kh) + ((size_t)(b * NH + h) * NT + n0) * NDH;
    int d = tid & 63, tb = tid >> 6;
    float gg = g[d] * scl, bb2 = bb[d] * scl;
#pragma unroll
    for (int t = tb; t < 128; t += 4) {
      float val = (Yl[d * 130 + t] - mu[t]) * rs[t] * gg + bb2;
      out[(size_t)t * NDH + d] = (bf16)val;
    }
  } else {
    f16* out = Vh + (size_t)(b * NH + h) * NDH * NT + n0;
    int t = tid & 127, db = tid >> 7;
#pragma unroll
    for (int d = db; d < 64; d += 2) {
      float val = (Yl[d * 130 + t] - mu[t]) * rs[t] * gv[d] + bbv[d];
      out[(size_t)d * NT + t] = (f16)val;
    }
  }
}

// ---------------- K4: flash attention v3 (register softmax) ----------------
// grid (T/64, B*H), block 256 = 4 waves; wave w owns keys [w*32, w*32+32)
// of each 128-key tile, all 64 q. S^T = K·Q^T via bf16 K=32 MFMA; its C/D
// layout (q=lane&15, key=quad*4+reg) equals the f16 K=16 MFMA A-layout, so
// exp stays in registers. PV: A=exp(S^T) f16, B=V[d][k] f16. No in-loop LDS.
__global__ __launch_bounds__(256, 2) void k_attn(
    const bf16* __restrict__ Qh, const bf16* __restrict__ Kh,
    const f16* __restrict__ Vh,
    const float* __restrict__ kmf, const int* __restrict__ qmask,
    bf16* __restrict__ xa)  // [B][T][E]
{
  int bh = blockIdx.y, b = bh >> 3, h = bh & 7;
  int q0 = blockIdx.x * 64;
  const bf16* Q = Qh + (size_t)bh * NT * NDH;
  const bf16* K = Kh + (size_t)bh * NT * NDH;
  const f16*  V = Vh + (size_t)bh * NDH * NT;

  __shared__ __align__(16) char smem[2 * 64 * 68 * 4 + 4 * 64 * 4]; // 35840 B
  float* OlA  = (float*)smem;                     // [64][68]
  float* OlB  = (float*)(smem + 64 * 68 * 4);     // [64][68]
  float* denl = (float*)(smem + 2 * 64 * 68 * 4); // [4][64]

  int tid = threadIdx.x, lane = tid & 63, w = tid >> 6;
  int quad = lane >> 4, l15 = lane & 15;
  const int ko = w * 32;

  // Q as B-operand: lane&15 = q, k(d) = quad*8+j
  bf16x8 qb[4][2];
#pragma unroll
  for (int qs = 0; qs < 4; qs++)
#pragma unroll
    for (int hf = 0; hf < 2; hf++)
      qb[qs][hf] = *(const bf16x8*)(Q + (size_t)(q0 + qs * 16 + l15) * NDH + hf * 32 + quad * 8);

  const bf16*  Kb = K + (size_t)(ko + l15) * NDH + quad * 8;
  const f16*   Vb = V + (size_t)l15 * NT + ko + quad * 4;
  const float* Mb = kmf + b * NT + ko + quad * 4;

  f32x4 acco[4][4] = {};   // [qs][ds]  row q=quad*4+r, col d=l15
  float den[4] = {};       // per-lane partial den for q = qs*16 + l15

  // current-iter K/V fragments (register double buffer)
  bf16x8 ka[2][2];   // [kt][hf]: A-operand of QK^T (m=key)
  f16x4  vb[4][2];   // [ds][kt]: B-operand of PV (n=d, k=key)
#pragma unroll
  for (int kt = 0; kt < 2; kt++)
#pragma unroll
    for (int hf = 0; hf < 2; hf++)
      ka[kt][hf] = *(const bf16x8*)(Kb + (size_t)(kt * 16) * NDH + hf * 32);
#pragma unroll
  for (int ds = 0; ds < 4; ds++)
#pragma unroll
    for (int kt = 0; kt < 2; kt++)
      vb[ds][kt] = *(const f16x4*)(Vb + (size_t)(ds * 16) * NT + kt * 16);

  for (int k0 = 0; k0 < NT; k0 += 128) {
    int k1 = (k0 + 128) & (NT - 1);   // wrap: last-iter prefetch unused
    bf16x8 nka[2][2];
    f16x4  nvb[4][2];
#pragma unroll
    for (int kt = 0; kt < 2; kt++)
#pragma unroll
      for (int hf = 0; hf < 2; hf++)
        nka[kt][hf] = *(const bf16x8*)(Kb + (size_t)(k1 + kt * 16) * NDH + hf * 32);
#pragma unroll
    for (int ds = 0; ds < 4; ds++)
#pragma unroll
      for (int kt = 0; kt < 2; kt++)
        nvb[ds][kt] = *(const f16x4*)(Vb + (size_t)(ds * 16) * NT + k1 + kt * 16);

    float4 kmv0 = *(const float4*)(Mb + k0);
    float4 kmv1 = *(const float4*)(Mb + k0 + 16);

#pragma unroll
    for (int kt = 0; kt < 2; kt++) {
      const float4 kmv = kt ? kmv1 : kmv0;
      // S^T tile: D[m=key][n=q]; C-layout: q=l15, key=quad*4+r
      f32x4 s[4];
#pragma unroll
      for (int qs = 0; qs < 4; qs++) {
        f32x4 z = {};
        z = MFMA_BF16(ka[kt][0], qb[qs][0], z);
        z = MFMA_BF16(ka[kt][1], qb[qs][1], z);
        s[qs] = z;
      }
      // exp + mask + den + pack to f16 A-frag (k = quad*4 + r)
      f16x4 pa[4];
#pragma unroll
      for (int qs = 0; qs < 4; qs++) {
        float p0 = __expf(s[qs][0]) * kmv.x;
        float p1 = __expf(s[qs][1]) * kmv.y;
        float p2 = __expf(s[qs][2]) * kmv.z;
        float p3 = __expf(s[qs][3]) * kmv.w;
        den[qs] += (p0 + p1) + (p2 + p3);
        f16x4 pv; pv[0] = (f16)p0; pv[1] = (f16)p1; pv[2] = (f16)p2; pv[3] = (f16)p3;
        pa[qs] = pv;
      }
      // O += P·V over these 16 keys
#pragma unroll
      for (int qs = 0; qs < 4; qs++)
#pragma unroll
        for (int ds = 0; ds < 4; ds++)
          acco[qs][ds] = MFMA_F16_K16(pa[qs], vb[ds][kt], acco[qs][ds]);
    }

#pragma unroll
    for (int kt = 0; kt < 2; kt++)
#pragma unroll
      for (int hf = 0; hf < 2; hf++)
        ka[kt][hf] = nka[kt][hf];
#pragma unroll
    for (int ds = 0; ds < 4; ds++)
#pragma unroll
      for (int kt = 0; kt < 2; kt++)
        vb[ds][kt] = nvb[ds][kt];
  }

  // reduce den across the 4 quads (q = qs*16 + l15 lives in all quads)
#pragma unroll
  for (int qs = 0; qs < 4; qs++) {
    den[qs] += __shfl_xor(den[qs], 16);
    den[qs] += __shfl_xor(den[qs], 32);
  }
  if (quad == 0)
#pragma unroll
    for (int qs = 0; qs < 4; qs++)
      denl[w * 64 + qs * 16 + l15] = den[qs];

  // cross-wave O combine: waves {0,1}->OlA, {2,3}->OlB, then sum at read
  float* Obuf = (w < 2) ? OlA : OlB;
  if ((w & 1) == 0) {
#pragma unroll
    for (int qs = 0; qs < 4; qs++)
#pragma unroll
      for (int ds = 0; ds < 4; ds++)
#pragma unroll
        for (int r = 0; r < 4; r++)
          Obuf[(qs * 16 + quad * 4 + r) * 68 + ds * 16 + l15] = acco[qs][ds][r];
  }
  __syncthreads();
  if (w & 1) {
#pragma unroll
    for (int qs = 0; qs < 4; qs++)
#pragma unroll
      for (int ds = 0; ds < 4; ds++)
#pragma unroll
        for (int r = 0; r < 4; r++)
          Obuf[(qs * 16 + quad * 4 + r) * 68 + ds * 16 + l15] += acco[qs][ds][r];
  }
  __syncthreads();

#pragma unroll
  for (int i = 0; i < 16; i++) {
    int ql = w * 16 + i;
    float dtot = denl[ql] + denl[64 + ql] + denl[128 + ql] + denl[192 + ql];
    float qm = (float)qmask[b * NT + q0 + ql];
    float inv = qm / dtot;   // masked query -> exact 0
    float val = (OlA[ql * 68 + lane] + OlB[ql * 68 + lane]) * inv;
    xa[((size_t)b * NT + q0 + ql) * NE + h * NDH + lane] = (bf16)val;
  }
}

// ---------------- K5: output projection (64x64 tiles, 512 blocks) ----------
__global__ __launch_bounds__(256) void k_oproj(
    const bf16* __restrict__ A,    // WnO [512][512]
    const bf16* __restrict__ xab,  // [B][T][E]
    const float* __restrict__ bo, float* __restrict__ out)
{
  int b = blockIdx.z;
  const bf16* Bm = xab + (size_t)b * NT * NE;
  int m0 = blockIdx.y * 64, n0 = blockIdx.x * 64;

  __shared__ __align__(16) char smem[16384];
  bf16* Al = (bf16*)smem;           // [64][64] swizzled
  bf16* Bl = (bf16*)(smem + 8192);  // [64][64] swizzled

  int tid = threadIdx.x, lane = tid & 63, w = tid >> 6;
  int mh = (w & 1) * 32, nh = (w >> 1) * 32;
  f32x4 acc[2][2] = {};

  for (int k0 = 0; k0 < NE; k0 += 64) {
    __syncthreads();
#pragma unroll
    for (int i = 0; i < 2; i++) {
      int row = (w << 4) + (i << 3) + (lane >> 3);
      int chg = (lane & 7) ^ (row & 7);
      gl_lds16(A + (m0 + row) * NE + k0 + (chg << 3),
               Al + ((w << 4) + (i << 3)) * 64);
    }
#pragma unroll
    for (int i = 0; i < 2; i++) {
      int row = (w << 4) + (i << 3) + (lane >> 3);
      int chg = (lane & 7) ^ (row & 7);
      gl_lds16(Bm + (size_t)(n0 + row) * NE + k0 + (chg << 3),
               Bl + ((w << 4) + (i << 3)) * 64);
    }
    __syncthreads();
#pragma unroll
    for (int kk = 0; kk < 64; kk += 32) {
      bf16x8 af[2], bfv[2];
#pragma unroll
      for (int ms = 0; ms < 2; ms++) {
        int row = mh + ms * 16 + (lane & 15);
        af[ms] = *(const bf16x8*)(Al + row * 64 +
                   ((((kk >> 3) + (lane >> 4)) ^ (row & 7)) << 3));
      }
#pragma unroll
      for (int ns = 0; ns < 2; ns++) {
        int row = nh + ns * 16 + (lane & 15);
        bfv[ns] = *(const bf16x8*)(Bl + row * 64 +
                   ((((kk >> 3) + (lane >> 4)) ^ (row & 7)) << 3));
      }
#pragma unroll
      for (int ms = 0; ms < 2; ms++)
#pragma unroll
        for (int ns = 0; ns < 2; ns++)
          acc[ms][ns] = MFMA_BF16(af[ms], bfv[ns], acc[ms][ns]);
    }
  }

#pragma unroll
  for (int ms = 0; ms < 2; ms++)
#pragma unroll
    for (int ns = 0; ns < 2; ns++)
#pragma unroll
      for (int r = 0; r < 4; r++) {
        int o = m0 + mh + ms * 16 + ((lane >> 4) << 2) + r;
        int t = n0 + nh + ns * 16 + (lane & 15);
        out[(size_t)b * NE * NT + (size_t)o * NT + t] = acc[ms][ns][r] + bo[o];
      }
}

// ---------------------------------------------------------------------------
extern "C" void kernel_launch(void* const* d_in, const int* in_sizes, int n_in,
                              void* d_out, int out_size, void* d_ws, size_t ws_size,
                              hipStream_t stream)
{
  const float* q  = (const float*)d_in[0];
  const float* k  = (const float*)d_in[1];
  const float* v  = (const float*)d_in[2];
  const int*   qm = (const int*)d_in[3];
  const int*   km = (const int*)d_in[4];
  const int*   vm = (const int*)d_in[5];
  const float* Wq = (const float*)d_in[6];  const float* bq = (const float*)d_in[7];
  const float* Wk = (const float*)d_in[8];  const float* bk = (const float*)d_in[9];
  const float* Wv = (const float*)d_in[10]; const float* bv = (const float*)d_in[11];
  const float* Wo = (const float*)d_in[12]; const float* bo = (const float*)d_in[13];
  const float* gq = (const float*)d_in[14]; const float* bbq = (const float*)d_in[15];
  const float* gk = (const float*)d_in[16]; const float* bbk = (const float*)d_in[17];
  const float* gv = (const float*)d_in[18]; const float* bbv = (const float*)d_in[19];
  float* out = (float*)d_out;

  char* wsb = (char*)d_ws;
  bf16*  Wn  = (bf16*)(wsb);                        //  2 MiB: 4x[512][512]
  bf16*  xT  = (bf16*)(wsb + (2ull  << 20));        // 12 MiB: 3x[B][T][E]
  bf16*  Qh  = (bf16*)(wsb + (14ull << 20));        //  4 MiB: [B][H][T][DH]
  bf16*  Kh  = (bf16*)(wsb + (18ull << 20));        //  4 MiB
  f16*   Vh  = (f16*) (wsb + (22ull << 20));        //  4 MiB: [B][H][DH][T] f16
  bf16*  xa  = (bf16*)(wsb + (26ull << 20));        //  4 MiB: [B][T][E]
  float* kmf = (float*)(wsb + (30ull << 20));       // 16 KiB: [B][T]

  k_wstd <<<dim3(512, 5),   64,  0, stream>>>(Wq, Wk, Wv, Wo, km, Wn, kmf);
  k_trans<<<dim3(32, 8, 6), 256, 0, stream>>>(q, k, v, qm, km, vm, xT);
  k_proj <<<dim3(16, 8, 6), 256, 0, stream>>>(Wn, xT, bq, bk, bv,
                                              gq, bbq, gk, bbk, gv, bbv,
                                              Qh, Kh, Vh);
  k_attn <<<dim3(32, 16),   256, 0, stream>>>(Qh, Kh, Vh, kmf, qm, xa);
  k_oproj<<<dim3(32, 8, 2), 256, 0, stream>>>(Wn + 3 * NE * NE, xa, bo, out);
}